// Round 5
// baseline (2811.832 us; speedup 1.0000x reference)
//
#include <hip/hip_runtime.h>
#include <hip/hip_bf16.h>

#define NN 50000
#define NE 300000
#define NBATCH 64
#define HC 512
#define DC 3096

typedef unsigned int u32;
typedef unsigned long long u64;

// ---------------- graph prep ----------------
__global__ void k_deg(const int* __restrict__ ei, int* __restrict__ degc){
  int e = blockIdx.x*256 + threadIdx.x;
  if (e < NE) atomicAdd(&degc[ei[NE + e]], 1);   // dst = row 1
}
__global__ void k_gcnt(const int* __restrict__ batch, int* __restrict__ gcnt){
  int i = blockIdx.x*256 + threadIdx.x;
  if (i < NN) atomicAdd(&gcnt[batch[i]], 1);
}
__global__ void k_dis(const int* __restrict__ degc, float* __restrict__ dis){
  int i = blockIdx.x*256 + threadIdx.x;
  if (i < NN) dis[i] = rsqrtf((float)degc[i] + 1.0f);
}
__global__ __launch_bounds__(1024) void k_scan(const int* __restrict__ cnt, int* __restrict__ rowp){
  const int CH = (NN + 1023)/1024;   // 49
  int lid = threadIdx.x;
  int begin = lid*CH;
  int s = 0;
  for (int j=0;j<CH;j++){ int i=begin+j; if (i<NN) s += cnt[i]; }
  __shared__ int buf[1024];
  buf[lid] = s; __syncthreads();
  for (int off=1; off<1024; off<<=1){
    int t = (lid>=off)? buf[lid-off] : 0; __syncthreads();
    buf[lid] += t; __syncthreads();
  }
  int run = buf[lid] - s;   // exclusive prefix of this chunk
  for (int j=0;j<CH;j++){ int i=begin+j; if (i<NN){ rowp[i]=run; run += cnt[i]; } }
  if (lid==1023) rowp[NN] = buf[1023];
}
__global__ void k_gstart(const int* __restrict__ gcnt, int* __restrict__ gstart){
  int b = threadIdx.x;
  if (b < NBATCH){ int s=0; for (int j=0;j<b;j++) s += gcnt[j]; gstart[b]=s; }
}
__global__ void k_fill(const int* __restrict__ ei, const int* __restrict__ rowp,
                       int* __restrict__ cursor, int* __restrict__ col){
  int e = blockIdx.x*256 + threadIdx.x;
  if (e < NE){
    int d = ei[NE + e];
    int p = atomicAdd(&cursor[d], 1);
    col[rowp[d] + p] = ei[e];   // src
  }
}

// ---------------- face selection (2 smallest ||xy|| per graph, stable tie-break) ----------------
__global__ void k_face1(const float* __restrict__ x, const int* __restrict__ batch, u64* __restrict__ key1){
  int i = blockIdx.x*256 + threadIdx.x;
  if (i >= NN) return;
  float x0 = x[i*8+0], x1 = x[i*8+1];
  float len = sqrtf(x0*x0 + x1*x1);
  u64 key = ((u64)__float_as_uint(len) << 32) | (u32)i;
  atomicMin(&key1[batch[i]], key);
}
__global__ void k_face2(const float* __restrict__ x, const int* __restrict__ batch,
                        const u64* __restrict__ key1, u64* __restrict__ key2){
  int i = blockIdx.x*256 + threadIdx.x;
  if (i >= NN) return;
  int b = batch[i];
  if ((u32)(key1[b] & 0xffffffffu) == (u32)i) return;
  float x0 = x[i*8+0], x1 = x[i*8+1];
  float len = sqrtf(x0*x0 + x1*x1);
  u64 key = ((u64)__float_as_uint(len) << 32) | (u32)i;
  atomicMin(&key2[b], key);
}
__global__ void k_face3(const float* __restrict__ x, const u64* __restrict__ key1,
                        const u64* __restrict__ key2, float* __restrict__ comb){
  int b = threadIdx.x;
  if (b >= NBATCH) return;
  u32 i1 = (u32)(key1[b] & 0xffffffffu);
  u32 i2 = (u32)(key2[b] & 0xffffffffu);
  float* row = comb + (size_t)b*DC;
  for (int j=0;j<8;j++){
    row[j]      = x[(size_t)i1*8 + j];
    row[8 + j]  = x[(size_t)i2*8 + j];
    row[16 + j] = 0.f;
  }
}

// ---------------- layer 1 transform: h2 = x(N,8) @ W1(8,512) ----------------
__global__ __launch_bounds__(256) void k_gemm1(const float* __restrict__ x, const float* __restrict__ W1,
                                               float* __restrict__ h2){
  int g = blockIdx.x*256 + threadIdx.x;
  if (g >= NN*HC) return;
  int i = g >> 9, c = g & 511;
  const float4* xp = (const float4*)(x + (size_t)i*8);
  float4 x0 = xp[0], x1 = xp[1];
  float acc = 0.f;
  acc = fmaf(x0.x, W1[0*HC + c], acc);
  acc = fmaf(x0.y, W1[1*HC + c], acc);
  acc = fmaf(x0.z, W1[2*HC + c], acc);
  acc = fmaf(x0.w, W1[3*HC + c], acc);
  acc = fmaf(x1.x, W1[4*HC + c], acc);
  acc = fmaf(x1.y, W1[5*HC + c], acc);
  acc = fmaf(x1.z, W1[6*HC + c], acc);
  acc = fmaf(x1.w, W1[7*HC + c], acc);
  h2[g] = acc;
}

// ---------------- big GEMM: C(M,512) = A(M,512) @ W(512,512), 128x128 tile, 8x8 micro ----------------
__global__ __launch_bounds__(256) void gemm_nk(const float* __restrict__ A, const float* __restrict__ W,
                                               float* __restrict__ C, int M){
  __shared__ float As[16][132];
  __shared__ float Ws[16][132];
  const int tid = threadIdx.x;
  const int r0 = blockIdx.x*128, c0 = blockIdx.y*128;
  const int tx = tid & 15, ty = tid >> 4;
  float acc[8][8];
  #pragma unroll
  for (int i=0;i<8;i++)
    #pragma unroll
    for (int j=0;j<8;j++) acc[i][j]=0.f;
  for (int k0=0; k0<512; k0+=16){
    {
      int m = tid >> 1, kk = (tid & 1)*8;
      int row = r0 + m;
      float4 v0 = make_float4(0,0,0,0), v1 = make_float4(0,0,0,0);
      if (row < M){
        const float4* p = (const float4*)(A + (size_t)row*512 + k0 + kk);
        v0 = p[0]; v1 = p[1];
      }
      As[kk+0][m]=v0.x; As[kk+1][m]=v0.y; As[kk+2][m]=v0.z; As[kk+3][m]=v0.w;
      As[kk+4][m]=v1.x; As[kk+5][m]=v1.y; As[kk+6][m]=v1.z; As[kk+7][m]=v1.w;
    }
    {
      int k = tid >> 4, c = (tid & 15)*8;
      const float4* p = (const float4*)(W + (size_t)(k0 + k)*512 + c0 + c);
      float4 w0 = p[0], w1 = p[1];
      *(float4*)&Ws[k][c]   = w0;
      *(float4*)&Ws[k][c+4] = w1;
    }
    __syncthreads();
    #pragma unroll
    for (int k=0;k<16;k++){
      float a[8], b[8];
      #pragma unroll
      for (int i=0;i<8;i++) a[i] = As[k][ty*8 + i];
      #pragma unroll
      for (int j=0;j<8;j++) b[j] = Ws[k][tx*8 + j];
      #pragma unroll
      for (int i=0;i<8;i++)
        #pragma unroll
        for (int j=0;j<8;j++) acc[i][j] = fmaf(a[i], b[j], acc[i][j]);
    }
    __syncthreads();
  }
  #pragma unroll
  for (int i=0;i<8;i++){
    int row = r0 + ty*8 + i;
    if (row < M){
      float4* q = (float4*)(C + (size_t)row*512 + c0 + tx*8);
      q[0] = make_float4(acc[i][0],acc[i][1],acc[i][2],acc[i][3]);
      q[1] = make_float4(acc[i][4],acc[i][5],acc[i][6],acc[i][7]);
    }
  }
}

// ---------------- aggregation: act = relu(dis_i * sum_j dis_j*h2_j + h2_i*dis_i^2 + b) ----------------
__global__ __launch_bounds__(256) void k_agg(const float* __restrict__ h2, const float* __restrict__ dis,
    const int* __restrict__ rowp, const int* __restrict__ col, const float* __restrict__ bias,
    float* __restrict__ act){
  int node = blockIdx.x*4 + (threadIdx.x >> 6);
  if (node >= NN) return;
  int lane = threadIdx.x & 63;
  int c0 = lane*8;
  float acc[8] = {0,0,0,0,0,0,0,0};
  int e0 = rowp[node], e1 = rowp[node+1];
  for (int e=e0; e<e1; e++){
    int j = col[e];
    float dj = dis[j];
    const float4* p = (const float4*)(h2 + (size_t)j*HC + c0);
    float4 v0 = p[0], v1 = p[1];
    acc[0]=fmaf(dj,v0.x,acc[0]); acc[1]=fmaf(dj,v0.y,acc[1]);
    acc[2]=fmaf(dj,v0.z,acc[2]); acc[3]=fmaf(dj,v0.w,acc[3]);
    acc[4]=fmaf(dj,v1.x,acc[4]); acc[5]=fmaf(dj,v1.y,acc[5]);
    acc[6]=fmaf(dj,v1.z,acc[6]); acc[7]=fmaf(dj,v1.w,acc[7]);
  }
  float di = dis[node];
  float sn = di*di;
  const float4* hp = (const float4*)(h2 + (size_t)node*HC + c0);
  float4 h0 = hp[0], h1 = hp[1];
  const float4* bp = (const float4*)(bias + c0);
  float4 b0 = bp[0], b1v = bp[1];
  float o[8];
  o[0]=fmaf(di,acc[0], fmaf(sn,h0.x, b0.x));
  o[1]=fmaf(di,acc[1], fmaf(sn,h0.y, b0.y));
  o[2]=fmaf(di,acc[2], fmaf(sn,h0.z, b0.z));
  o[3]=fmaf(di,acc[3], fmaf(sn,h0.w, b0.w));
  o[4]=fmaf(di,acc[4], fmaf(sn,h1.x, b1v.x));
  o[5]=fmaf(di,acc[5], fmaf(sn,h1.y, b1v.y));
  o[6]=fmaf(di,acc[6], fmaf(sn,h1.z, b1v.z));
  o[7]=fmaf(di,acc[7], fmaf(sn,h1.w, b1v.w));
  #pragma unroll
  for (int i=0;i<8;i++) o[i] = fmaxf(o[i], 0.f);
  float4* q = (float4*)(act + (size_t)node*HC + c0);
  q[0] = make_float4(o[0],o[1],o[2],o[3]);
  q[1] = make_float4(o[4],o[5],o[6],o[7]);
}

// ---------------- readout: per-graph sum of act rows ----------------
__global__ __launch_bounds__(256) void k_readout(const float* __restrict__ act, const int* __restrict__ gstart,
                                                 const int* __restrict__ gcnt, float* __restrict__ gsum){
  int b = blockIdx.x >> 2, part = blockIdx.x & 3;
  int start = gstart[b], cnt = gcnt[b];
  int c = threadIdx.x;
  float a0=0.f, a1=0.f;
  for (int r=part; r<cnt; r+=4){
    const float* row = act + (size_t)(start + r)*HC;
    a0 += row[c]; a1 += row[c + 256];
  }
  atomicAdd(&gsum[b*HC + c], a0);
  atomicAdd(&gsum[b*HC + c + 256], a1);
}
__global__ void k_readout_write(const float* __restrict__ gsum, const int* __restrict__ gcnt,
                                float* __restrict__ comb, int l){
  int g = blockIdx.x*256 + threadIdx.x;
  if (g >= NBATCH*HC) return;
  int b = g >> 9, c = g & 511;
  float s = gsum[g];
  float* row = comb + (size_t)b*DC + 24 + l*1024;
  row[c] = s / (float)gcnt[b];
  row[512 + c] = s;
}

// ---------------- head input assembly ----------------
__global__ void k_in0(const float* __restrict__ tp, const float* __restrict__ comb, float* __restrict__ dst){
  int g = blockIdx.x*256 + threadIdx.x;
  if (g >= NBATCH*3098) return;
  int b = g / 3098, c = g - b*3098;
  dst[g] = (c < 2) ? tp[b*2 + c] : comb[(size_t)b*DC + c - 2];
}
__global__ void k_inv(const float* __restrict__ pos, const float* __restrict__ comb, float* __restrict__ dst){
  int g = blockIdx.x*256 + threadIdx.x;
  if (g >= NBATCH*3098) return;
  int b = g / 3098, c = g - b*3098;
  dst[g] = (c < 2) ? pos[b*2 + c] : comb[(size_t)b*DC + c - 2];
}
__global__ void k_pvc(const float* __restrict__ pos, const float* __restrict__ vec,
                      const float* __restrict__ comb, float* __restrict__ dst){
  int g = blockIdx.x*256 + threadIdx.x;
  if (g >= NBATCH*3102) return;
  int b = g / 3102, c = g - b*3102;
  float v;
  if (c < 2) v = pos[b*2 + c];
  else if (c < 6) v = vec[b*4 + c - 2];
  else v = comb[(size_t)b*DC + c - 6];
  dst[g] = v;
}

// ---------------- head GEMM: out(64,Nw) += A(64,K) @ W(K,Nw), split-K, atomic partials ----------------
__global__ __launch_bounds__(256) void head_gemm(const float* __restrict__ A, int K,
    const float* __restrict__ W, int Nw, float* __restrict__ out){
  __shared__ float As[32][68];
  __shared__ float Ws[32][68];
  const int tid = threadIdx.x;
  const int c0 = blockIdx.x*64;
  const int k0 = blockIdx.y*800;
  const int kend = min(K, k0 + 800);
  const int tx = tid & 15, ty = tid >> 4;
  float acc[4][4];
  #pragma unroll
  for (int i=0;i<4;i++)
    #pragma unroll
    for (int j=0;j<4;j++) acc[i][j]=0.f;
  for (int kt=k0; kt<kend; kt+=32){
    {
      int m = tid & 63, kk = (tid >> 6)*8;
      #pragma unroll
      for (int j=0;j<8;j++){
        int k = kt + kk + j;
        As[kk+j][m] = (k < kend) ? A[(size_t)m*K + k] : 0.f;
      }
    }
    {
      int kk = tid >> 3, c = (tid & 7)*8;
      float f[8] = {0,0,0,0,0,0,0,0};
      if (kt + kk < kend){
        const float* wp = W + (size_t)(kt + kk)*Nw + c0 + c;
        #pragma unroll
        for (int j=0;j<8;j++) f[j] = wp[j];
      }
      *(float4*)&Ws[kk][c]   = make_float4(f[0],f[1],f[2],f[3]);
      *(float4*)&Ws[kk][c+4] = make_float4(f[4],f[5],f[6],f[7]);
    }
    __syncthreads();
    #pragma unroll
    for (int k=0;k<32;k++){
      float a[4], b[4];
      #pragma unroll
      for (int i=0;i<4;i++) a[i] = As[k][ty*4 + i];
      #pragma unroll
      for (int j=0;j<4;j++) b[j] = Ws[k][tx*4 + j];
      #pragma unroll
      for (int i=0;i<4;i++)
        #pragma unroll
        for (int j=0;j<4;j++) acc[i][j] = fmaf(a[i], b[j], acc[i][j]);
    }
    __syncthreads();
  }
  #pragma unroll
  for (int i=0;i<4;i++)
    #pragma unroll
    for (int j=0;j<4;j++)
      atomicAdd(&out[(size_t)(ty*4 + i)*Nw + c0 + tx*4 + j], acc[i][j]);
}

__global__ void k_bias_relu(float* __restrict__ buf, const float* __restrict__ bias, int Nw, int do_relu){
  int g = blockIdx.x*256 + threadIdx.x;
  if (g >= NBATCH*Nw) return;
  int c = g % Nw;
  float v = buf[g] + bias[c];
  buf[g] = do_relu ? fmaxf(v, 0.f) : v;
}

// tiny final projection: out(64,Nw) = A(64,K) @ W(K,Nw) + b ; Nw <= 4
__global__ void k_tiny(const float* __restrict__ A, int K, const float* __restrict__ W, int Nw,
                       const float* __restrict__ bias, float* __restrict__ out){
  int g = threadIdx.x;
  if (g >= NBATCH*Nw) return;
  int b = g / Nw, c = g - b*Nw;
  float acc = bias[c];
  const float* a = A + (size_t)b*K;
  for (int k=0;k<K;k++) acc = fmaf(a[k], W[(size_t)k*Nw + c], acc);
  out[g] = acc;
}

__global__ void k_final(const float* __restrict__ pos, const float* __restrict__ sc,
                        const float* __restrict__ rot, const float* __restrict__ vec,
                        float* __restrict__ out){
  int g = blockIdx.x*256 + threadIdx.x;
  if (g >= NBATCH*8) return;
  int b = g >> 3, j = g & 7;
  float v;
  if (j < 2) v = pos[b*2 + j];
  else if (j == 2) v = sc[b];
  else if (j == 3) v = rot[b];
  else v = vec[b*4 + j - 4];
  out[g] = v;
}

// ---------------- host ----------------
static inline int cdiv(int a, int b){ return (a + b - 1)/b; }

extern "C" void kernel_launch(void* const* d_in, const int* in_sizes, int n_in,
                              void* d_out, int out_size, void* d_ws, size_t ws_size,
                              hipStream_t stream)
{
  (void)in_sizes; (void)n_in; (void)out_size;
  const float* x   = (const float*)d_in[0];
  const int* ei    = (const int*)d_in[1];
  const int* batch = (const int*)d_in[2];
  const float* tpos= (const float*)d_in[3];
  const float* W1 = (const float*)d_in[4];  const float* b1 = (const float*)d_in[5];
  const float* W2 = (const float*)d_in[6];  const float* b2 = (const float*)d_in[7];
  const float* W3 = (const float*)d_in[8];  const float* b3 = (const float*)d_in[9];
  const float* ph1w = (const float*)d_in[10]; const float* ph1b = (const float*)d_in[11];
  const float* ph2w = (const float*)d_in[12]; const float* ph2b = (const float*)d_in[13];
  const float* posw = (const float*)d_in[14]; const float* posb = (const float*)d_in[15];
  const float* vh1w = (const float*)d_in[16]; const float* vh1b = (const float*)d_in[17];
  const float* vh2w = (const float*)d_in[18]; const float* vh2b = (const float*)d_in[19];
  const float* vecw = (const float*)d_in[20]; const float* vecb = (const float*)d_in[21];
  const float* sh1w = (const float*)d_in[22]; const float* sh1b = (const float*)d_in[23];
  const float* sh2w = (const float*)d_in[24]; const float* sh2b = (const float*)d_in[25];
  const float* scw  = (const float*)d_in[26]; const float* scb  = (const float*)d_in[27];
  const float* rh1w = (const float*)d_in[28]; const float* rh1b = (const float*)d_in[29];
  const float* rh2w = (const float*)d_in[30]; const float* rh2b = (const float*)d_in[31];
  const float* rotw = (const float*)d_in[32]; const float* rotb = (const float*)d_in[33];
  float* out = (float*)d_out;

  char* w = (char*)d_ws;
  size_t off = 0;
  auto alloc = [&](size_t bytes) -> void* {
    void* p = w + off;
    off = (off + bytes + 255) & ~(size_t)255;
    return p;
  };
  float* h2   = (float*)alloc((size_t)NN*HC*4);
  float* act  = (float*)alloc((size_t)NN*HC*4);
  float* dis  = (float*)alloc((size_t)NN*4);
  int* degc   = (int*)alloc((size_t)NN*4);
  int* rowp   = (int*)alloc((size_t)(NN+1)*4);
  int* cursor = (int*)alloc((size_t)NN*4);
  int* col    = (int*)alloc((size_t)NE*4);
  int* gcnt   = (int*)alloc((size_t)NBATCH*4);
  int* gstart = (int*)alloc((size_t)NBATCH*4);
  u64* key1   = (u64*)alloc((size_t)NBATCH*8);
  u64* key2   = (u64*)alloc((size_t)NBATCH*8);
  float* gsum = (float*)alloc((size_t)NBATCH*HC*4);
  float* comb = (float*)alloc((size_t)NBATCH*DC*4);
  float* in0  = (float*)alloc((size_t)NBATCH*3098*4);
  float* t1   = (float*)alloc((size_t)NBATCH*1536*4);
  float* t2   = (float*)alloc((size_t)NBATCH*1536*4);
  float* inv  = (float*)alloc((size_t)NBATCH*3098*4);
  float* u1   = (float*)alloc((size_t)NBATCH*512*4);
  float* u2   = (float*)alloc((size_t)NBATCH*512*4);
  float* pvc  = (float*)alloc((size_t)NBATCH*3102*4);
  float* sb1  = (float*)alloc((size_t)NBATCH*512*4);
  float* sb2  = (float*)alloc((size_t)NBATCH*512*4);
  float* rb1  = (float*)alloc((size_t)NBATCH*512*4);
  float* rb2  = (float*)alloc((size_t)NBATCH*512*4);
  float* poso = (float*)alloc((size_t)NBATCH*2*4);
  float* veco = (float*)alloc((size_t)NBATCH*4*4);
  float* sco  = (float*)alloc((size_t)NBATCH*4);
  float* roto = (float*)alloc((size_t)NBATCH*4);
  if (off > ws_size) return;   // workspace insufficient — fail visibly

  // ---- graph prep ----
  hipMemsetAsync(degc, 0, (size_t)NN*4, stream);
  hipMemsetAsync(cursor, 0, (size_t)NN*4, stream);
  hipMemsetAsync(gcnt, 0, (size_t)NBATCH*4, stream);
  hipMemsetAsync(key1, 0xFF, (size_t)NBATCH*8, stream);
  hipMemsetAsync(key2, 0xFF, (size_t)NBATCH*8, stream);

  k_deg<<<cdiv(NE,256),256,0,stream>>>(ei, degc);
  k_gcnt<<<cdiv(NN,256),256,0,stream>>>(batch, gcnt);
  k_dis<<<cdiv(NN,256),256,0,stream>>>(degc, dis);
  k_scan<<<1,1024,0,stream>>>(degc, rowp);
  k_gstart<<<1,64,0,stream>>>(gcnt, gstart);
  k_fill<<<cdiv(NE,256),256,0,stream>>>(ei, rowp, cursor, col);
  k_face1<<<cdiv(NN,256),256,0,stream>>>(x, batch, key1);
  k_face2<<<cdiv(NN,256),256,0,stream>>>(x, batch, key1, key2);
  k_face3<<<1,64,0,stream>>>(x, key1, key2, comb);

  // ---- GCN layers ----
  // layer 1
  k_gemm1<<<cdiv(NN*HC,256),256,0,stream>>>(x, W1, h2);
  k_agg<<<cdiv(NN,4),256,0,stream>>>(h2, dis, rowp, col, b1, act);
  hipMemsetAsync(gsum, 0, (size_t)NBATCH*HC*4, stream);
  k_readout<<<NBATCH*4,256,0,stream>>>(act, gstart, gcnt, gsum);
  k_readout_write<<<cdiv(NBATCH*HC,256),256,0,stream>>>(gsum, gcnt, comb, 0);
  // layer 2
  gemm_nk<<<dim3(cdiv(NN,128),4),256,0,stream>>>(act, W2, h2, NN);
  k_agg<<<cdiv(NN,4),256,0,stream>>>(h2, dis, rowp, col, b2, act);
  hipMemsetAsync(gsum, 0, (size_t)NBATCH*HC*4, stream);
  k_readout<<<NBATCH*4,256,0,stream>>>(act, gstart, gcnt, gsum);
  k_readout_write<<<cdiv(NBATCH*HC,256),256,0,stream>>>(gsum, gcnt, comb, 1);
  // layer 3
  gemm_nk<<<dim3(cdiv(NN,128),4),256,0,stream>>>(act, W3, h2, NN);
  k_agg<<<cdiv(NN,4),256,0,stream>>>(h2, dis, rowp, col, b3, act);
  hipMemsetAsync(gsum, 0, (size_t)NBATCH*HC*4, stream);
  k_readout<<<NBATCH*4,256,0,stream>>>(act, gstart, gcnt, gsum);
  k_readout_write<<<cdiv(NBATCH*HC,256),256,0,stream>>>(gsum, gcnt, comb, 2);

  // ---- pos head ----
  k_in0<<<cdiv(NBATCH*3098,256),256,0,stream>>>(tpos, comb, in0);
  hipMemsetAsync(t1, 0, (size_t)NBATCH*1536*4, stream);
  head_gemm<<<dim3(1536/64, cdiv(3098,800)),256,0,stream>>>(in0, 3098, ph1w, 1536, t1);
  k_bias_relu<<<cdiv(NBATCH*1536,256),256,0,stream>>>(t1, ph1b, 1536, 1);
  hipMemsetAsync(t2, 0, (size_t)NBATCH*1536*4, stream);
  head_gemm<<<dim3(1536/64, cdiv(1536,800)),256,0,stream>>>(t1, 1536, ph2w, 1536, t2);
  k_bias_relu<<<cdiv(NBATCH*1536,256),256,0,stream>>>(t2, ph2b, 1536, 1);
  k_tiny<<<1,256,0,stream>>>(t2, 1536, posw, 2, posb, poso);

  // ---- vec head ----
  k_inv<<<cdiv(NBATCH*3098,256),256,0,stream>>>(poso, comb, inv);
  hipMemsetAsync(u1, 0, (size_t)NBATCH*512*4, stream);
  head_gemm<<<dim3(512/64, cdiv(3098,800)),256,0,stream>>>(inv, 3098, vh1w, 512, u1);
  k_bias_relu<<<cdiv(NBATCH*512,256),256,0,stream>>>(u1, vh1b, 512, 1);
  hipMemsetAsync(u2, 0, (size_t)NBATCH*512*4, stream);
  head_gemm<<<dim3(512/64, 1),256,0,stream>>>(u1, 512, vh2w, 512, u2);
  k_bias_relu<<<cdiv(NBATCH*512,256),256,0,stream>>>(u2, vh2b, 512, 1);
  k_tiny<<<1,256,0,stream>>>(u2, 512, vecw, 4, vecb, veco);

  // ---- pvc ----
  k_pvc<<<cdiv(NBATCH*3102,256),256,0,stream>>>(poso, veco, comb, pvc);

  // ---- scale head ----
  hipMemsetAsync(sb1, 0, (size_t)NBATCH*512*4, stream);
  head_gemm<<<dim3(512/64, cdiv(3102,800)),256,0,stream>>>(pvc, 3102, sh1w, 512, sb1);
  k_bias_relu<<<cdiv(NBATCH*512,256),256,0,stream>>>(sb1, sh1b, 512, 1);
  hipMemsetAsync(sb2, 0, (size_t)NBATCH*512*4, stream);
  head_gemm<<<dim3(512/64, 1),256,0,stream>>>(sb1, 512, sh2w, 512, sb2);
  k_bias_relu<<<cdiv(NBATCH*512,256),256,0,stream>>>(sb2, sh2b, 512, 1);
  k_tiny<<<1,256,0,stream>>>(sb2, 512, scw, 1, scb, sco);

  // ---- rot head ----
  hipMemsetAsync(rb1, 0, (size_t)NBATCH*512*4, stream);
  head_gemm<<<dim3(512/64, cdiv(3102,800)),256,0,stream>>>(pvc, 3102, rh1w, 512, rb1);
  k_bias_relu<<<cdiv(NBATCH*512,256),256,0,stream>>>(rb1, rh1b, 512, 1);
  hipMemsetAsync(rb2, 0, (size_t)NBATCH*512*4, stream);
  head_gemm<<<dim3(512/64, 1),256,0,stream>>>(rb1, 512, rh2w, 512, rb2);
  k_bias_relu<<<cdiv(NBATCH*512,256),256,0,stream>>>(rb2, rh2b, 512, 1);
  k_tiny<<<1,256,0,stream>>>(rb2, 512, rotw, 1, rotb, roto);

  // ---- final output ----
  k_final<<<cdiv(NBATCH*8,256),256,0,stream>>>(poso, sco, roto, veco, out);
}

// Round 8
// 2403.132 us; speedup vs baseline: 1.1701x; 1.1701x over previous
//
#include <hip/hip_runtime.h>
#include <hip/hip_bf16.h>

#define NN 50000
#define NE 300000
#define NBATCH 64
#define HC 512
#define DC 3096

typedef unsigned short u16;
typedef unsigned int u32;
typedef unsigned long long u64;
typedef __attribute__((ext_vector_type(8))) short s16x8;
typedef __attribute__((ext_vector_type(4))) float f32x4;

static __device__ __forceinline__ float bf2f(u16 u){ return __uint_as_float(((u32)u)<<16); }
static __device__ __forceinline__ u16 f2bf(float f){
  __hip_bfloat16 h = __float2bfloat16(f);
  return *reinterpret_cast<u16*>(&h);
}
// unpack 8 bf16 (as uint4) -> 8 floats
static __device__ __forceinline__ void bf8up(uint4 r, float* f){
  f[0]=__uint_as_float(r.x<<16); f[1]=__uint_as_float(r.x&0xffff0000u);
  f[2]=__uint_as_float(r.y<<16); f[3]=__uint_as_float(r.y&0xffff0000u);
  f[4]=__uint_as_float(r.z<<16); f[5]=__uint_as_float(r.z&0xffff0000u);
  f[6]=__uint_as_float(r.w<<16); f[7]=__uint_as_float(r.w&0xffff0000u);
}

// ---------------- graph prep ----------------
__global__ void k_deg(const int* __restrict__ ei, int* __restrict__ degc){
  int e = blockIdx.x*256 + threadIdx.x;
  if (e < NE) atomicAdd(&degc[ei[NE + e]], 1);
}
__global__ void k_gcnt(const int* __restrict__ batch, int* __restrict__ gcnt){
  int i = blockIdx.x*256 + threadIdx.x;
  if (i < NN) atomicAdd(&gcnt[batch[i]], 1);
}
__global__ void k_dis(const int* __restrict__ degc, float* __restrict__ dis){
  int i = blockIdx.x*256 + threadIdx.x;
  if (i < NN) dis[i] = rsqrtf((float)degc[i] + 1.0f);
}
__global__ __launch_bounds__(1024) void k_scan(const int* __restrict__ cnt, int* __restrict__ rowp){
  const int CH = (NN + 1023)/1024;
  int lid = threadIdx.x;
  int begin = lid*CH;
  int s = 0;
  for (int j=0;j<CH;j++){ int i=begin+j; if (i<NN) s += cnt[i]; }
  __shared__ int buf[1024];
  buf[lid] = s; __syncthreads();
  for (int off=1; off<1024; off<<=1){
    int t = (lid>=off)? buf[lid-off] : 0; __syncthreads();
    buf[lid] += t; __syncthreads();
  }
  int run = buf[lid] - s;
  for (int j=0;j<CH;j++){ int i=begin+j; if (i<NN){ rowp[i]=run; run += cnt[i]; } }
  if (lid==1023) rowp[NN] = buf[1023];
}
__global__ void k_gstart(const int* __restrict__ gcnt, int* __restrict__ gstart){
  int b = threadIdx.x;
  if (b < NBATCH){ int s=0; for (int j=0;j<b;j++) s += gcnt[j]; gstart[b]=s; }
}
__global__ void k_fill(const int* __restrict__ ei, const int* __restrict__ rowp,
                       int* __restrict__ cursor, int* __restrict__ col){
  int e = blockIdx.x*256 + threadIdx.x;
  if (e < NE){
    int d = ei[NE + e];
    int p = atomicAdd(&cursor[d], 1);
    col[rowp[d] + p] = ei[e];
  }
}

// ---------------- face selection ----------------
__global__ void k_face1(const float* __restrict__ x, const int* __restrict__ batch, u64* __restrict__ key1){
  int i = blockIdx.x*256 + threadIdx.x;
  if (i >= NN) return;
  float x0 = x[i*8+0], x1 = x[i*8+1];
  float len = sqrtf(x0*x0 + x1*x1);
  u64 key = ((u64)__float_as_uint(len) << 32) | (u32)i;
  atomicMin(&key1[batch[i]], key);
}
__global__ void k_face2(const float* __restrict__ x, const int* __restrict__ batch,
                        const u64* __restrict__ key1, u64* __restrict__ key2){
  int i = blockIdx.x*256 + threadIdx.x;
  if (i >= NN) return;
  int b = batch[i];
  if ((u32)(key1[b] & 0xffffffffu) == (u32)i) return;
  float x0 = x[i*8+0], x1 = x[i*8+1];
  float len = sqrtf(x0*x0 + x1*x1);
  u64 key = ((u64)__float_as_uint(len) << 32) | (u32)i;
  atomicMin(&key2[b], key);
}
__global__ void k_face3(const float* __restrict__ x, const u64* __restrict__ key1,
                        const u64* __restrict__ key2, float* __restrict__ comb){
  int b = threadIdx.x;
  if (b >= NBATCH) return;
  u32 i1 = (u32)(key1[b] & 0xffffffffu);
  u32 i2 = (u32)(key2[b] & 0xffffffffu);
  float* row = comb + (size_t)b*DC;
  for (int j=0;j<8;j++){
    row[j]      = x[(size_t)i1*8 + j];
    row[8 + j]  = x[(size_t)i2*8 + j];
    row[16 + j] = 0.f;
  }
}

// ---------------- layer 1 transform: h2 = x(N,8) @ W1(8,512), bf16 out ----------------
__global__ __launch_bounds__(256) void k_gemm1(const float* __restrict__ x, const float* __restrict__ W1,
                                               u16* __restrict__ h2){
  int g = blockIdx.x*256 + threadIdx.x;
  if (g >= NN*HC) return;
  int i = g >> 9, c = g & 511;
  const float4* xp = (const float4*)(x + (size_t)i*8);
  float4 x0 = xp[0], x1 = xp[1];
  float acc = 0.f;
  acc = fmaf(x0.x, W1[0*HC + c], acc);
  acc = fmaf(x0.y, W1[1*HC + c], acc);
  acc = fmaf(x0.z, W1[2*HC + c], acc);
  acc = fmaf(x0.w, W1[3*HC + c], acc);
  acc = fmaf(x1.x, W1[4*HC + c], acc);
  acc = fmaf(x1.y, W1[5*HC + c], acc);
  acc = fmaf(x1.z, W1[6*HC + c], acc);
  acc = fmaf(x1.w, W1[7*HC + c], acc);
  h2[g] = f2bf(acc);
}

// ---------------- W convert+transpose: Wt[n][k] = bf16(W[k][n]), 512x512 ----------------
__global__ __launch_bounds__(256) void k_convWT(const float* __restrict__ W, u16* __restrict__ Wt){
  __shared__ float t[32][33];
  int n0 = blockIdx.x*32, k0 = blockIdx.y*32;
  int tx = threadIdx.x & 31, ty = threadIdx.x >> 5;   // 32 x 8
  #pragma unroll
  for (int j=0;j<4;j++)
    t[ty*4+j][tx] = W[(size_t)(k0 + ty*4 + j)*512 + n0 + tx];
  __syncthreads();
  #pragma unroll
  for (int j=0;j<4;j++)
    Wt[(size_t)(n0 + ty*4 + j)*512 + k0 + tx] = f2bf(t[tx][ty*4+j]);
}

// ---------------- bf16 MFMA GEMM: C(M,512) = A(M,512) @ W(512,512); Wt[n][k] bf16 ----------------
// wave = 16-row stripe; 16 A-frags in regs; 32 n-tiles, 2 acc chains.
// 16x16x32 layouts: A/B: row|col = lane&15, k = (lane>>4)*8 + e. D: col = lane&15, row = (lane>>4)*4 + reg.
__global__ __launch_bounds__(256) void gemm_mfma(const u16* __restrict__ A, const u16* __restrict__ Wt,
                                                 u16* __restrict__ C, int M){
  int stripe = blockIdx.x*4 + (threadIdx.x >> 6);
  if (stripe >= (M >> 4)) return;
  int lane = threadIdx.x & 63;
  int r  = lane & 15;
  int ko = (lane >> 4) * 8;
  s16x8 a[16];
  const u16* arow = A + (size_t)(stripe*16 + r)*512 + ko;
  #pragma unroll
  for (int kt=0; kt<16; kt++)
    a[kt] = *(const s16x8*)(arow + kt*32);
  for (int nt=0; nt<32; nt+=2){
    const u16* b0 = Wt + (size_t)(nt*16 + r)*512 + ko;
    const u16* b1 = b0 + 16*512;
    f32x4 acc0 = {0.f,0.f,0.f,0.f};
    f32x4 acc1 = {0.f,0.f,0.f,0.f};
    #pragma unroll
    for (int kt=0; kt<16; kt++){
      s16x8 vb0 = *(const s16x8*)(b0 + kt*32);
      s16x8 vb1 = *(const s16x8*)(b1 + kt*32);
      acc0 = __builtin_amdgcn_mfma_f32_16x16x32_bf16(a[kt], vb0, acc0, 0, 0, 0);
      acc1 = __builtin_amdgcn_mfma_f32_16x16x32_bf16(a[kt], vb1, acc1, 0, 0, 0);
    }
    int drow = stripe*16 + ((lane >> 4) << 2);
    u16* cp0 = C + (size_t)drow*512 + nt*16 + r;
    u16* cp1 = cp0 + 16;
    #pragma unroll
    for (int q=0;q<4;q++){
      cp0[(size_t)q*512] = f2bf(acc0[q]);
      cp1[(size_t)q*512] = f2bf(acc1[q]);
    }
  }
}

// ---------------- aggregation (bf16 in/out): act = relu(dis_i*sum_j dis_j*h2_j + h2_i*dis_i^2 + b) ----------------
__global__ __launch_bounds__(256) void k_agg(const u16* __restrict__ h2, const float* __restrict__ dis,
    const int* __restrict__ rowp, const int* __restrict__ col, const float* __restrict__ bias,
    u16* __restrict__ act){
  int node = blockIdx.x*4 + (threadIdx.x >> 6);
  if (node >= NN) return;
  int lane = threadIdx.x & 63;
  int c0 = lane*8;
  float acc[8] = {0,0,0,0,0,0,0,0};
  int e0 = rowp[node], e1 = rowp[node+1];
  for (int e=e0; e<e1; e++){
    int j = col[e];
    float dj = dis[j];
    uint4 raw = *(const uint4*)(h2 + (size_t)j*HC + c0);
    float v[8]; bf8up(raw, v);
    #pragma unroll
    for (int i=0;i<8;i++) acc[i] = fmaf(dj, v[i], acc[i]);
  }
  float di = dis[node];
  float sn = di*di;
  uint4 sraw = *(const uint4*)(h2 + (size_t)node*HC + c0);
  float hs[8]; bf8up(sraw, hs);
  const float4* bp = (const float4*)(bias + c0);
  float4 b0 = bp[0], b1v = bp[1];
  float bb[8] = {b0.x,b0.y,b0.z,b0.w,b1v.x,b1v.y,b1v.z,b1v.w};
  u32 ow[4];
  #pragma unroll
  for (int i=0;i<4;i++){
    float o0 = fmaxf(fmaf(di,acc[2*i],   fmaf(sn,hs[2*i],   bb[2*i])),   0.f);
    float o1 = fmaxf(fmaf(di,acc[2*i+1], fmaf(sn,hs[2*i+1], bb[2*i+1])), 0.f);
    ow[i] = (u32)f2bf(o0) | ((u32)f2bf(o1) << 16);
  }
  *(uint4*)(act + (size_t)node*HC + c0) = make_uint4(ow[0],ow[1],ow[2],ow[3]);
}

// ---------------- readout (bf16 in) ----------------
__global__ __launch_bounds__(256) void k_readout(const u16* __restrict__ act, const int* __restrict__ gstart,
                                                 const int* __restrict__ gcnt, float* __restrict__ gsum){
  int b = blockIdx.x >> 2, part = blockIdx.x & 3;
  int start = gstart[b], cnt = gcnt[b];
  int c = threadIdx.x;
  float a0=0.f, a1=0.f;
  for (int r=part; r<cnt; r+=4){
    const u16* row = act + (size_t)(start + r)*HC;
    a0 += bf2f(row[c]); a1 += bf2f(row[c + 256]);
  }
  atomicAdd(&gsum[b*HC + c], a0);
  atomicAdd(&gsum[b*HC + c + 256], a1);
}
__global__ void k_readout_write(const float* __restrict__ gsum, const int* __restrict__ gcnt,
                                float* __restrict__ comb, int l){
  int g = blockIdx.x*256 + threadIdx.x;
  if (g >= NBATCH*HC) return;
  int b = g >> 9, c = g & 511;
  float s = gsum[g];
  float* row = comb + (size_t)b*DC + 24 + l*1024;
  row[c] = s / (float)gcnt[b];
  row[512 + c] = s;
}

// ---------------- head input assembly ----------------
__global__ void k_in0(const float* __restrict__ tp, const float* __restrict__ comb, float* __restrict__ dst){
  int g = blockIdx.x*256 + threadIdx.x;
  if (g >= NBATCH*3098) return;
  int b = g / 3098, c = g - b*3098;
  dst[g] = (c < 2) ? tp[b*2 + c] : comb[(size_t)b*DC + c - 2];
}
__global__ void k_inv(const float* __restrict__ pos, const float* __restrict__ comb, float* __restrict__ dst){
  int g = blockIdx.x*256 + threadIdx.x;
  if (g >= NBATCH*3098) return;
  int b = g / 3098, c = g - b*3098;
  dst[g] = (c < 2) ? pos[b*2 + c] : comb[(size_t)b*DC + c - 2];
}
__global__ void k_pvc(const float* __restrict__ pos, const float* __restrict__ vec,
                      const float* __restrict__ comb, float* __restrict__ dst){
  int g = blockIdx.x*256 + threadIdx.x;
  if (g >= NBATCH*3102) return;
  int b = g / 3102, c = g - b*3102;
  float v;
  if (c < 2) v = pos[b*2 + c];
  else if (c < 6) v = vec[b*4 + c - 2];
  else v = comb[(size_t)b*DC + c - 6];
  dst[g] = v;
}

// ---------------- head GEMM: out(64,Nw) += A(64,K) @ W(K,Nw), split-K atomic ----------------
__global__ __launch_bounds__(256) void head_gemm(const float* __restrict__ A, int K,
    const float* __restrict__ W, int Nw, float* __restrict__ out){
  __shared__ float As[32][68];
  __shared__ float Ws[32][68];
  const int tid = threadIdx.x;
  const int c0 = blockIdx.x*64;
  const int k0 = blockIdx.y*800;
  const int kend = min(K, k0 + 800);
  const int tx = tid & 15, ty = tid >> 4;
  float acc[4][4];
  #pragma unroll
  for (int i=0;i<4;i++)
    #pragma unroll
    for (int j=0;j<4;j++) acc[i][j]=0.f;
  for (int kt=k0; kt<kend; kt+=32){
    {
      int m = tid & 63, kk = (tid >> 6)*8;
      #pragma unroll
      for (int j=0;j<8;j++){
        int k = kt + kk + j;
        As[kk+j][m] = (k < kend) ? A[(size_t)m*K + k] : 0.f;
      }
    }
    {
      int kk = tid >> 3, c = (tid & 7)*8;
      float f[8] = {0,0,0,0,0,0,0,0};
      if (kt + kk < kend){
        const float* wp = W + (size_t)(kt + kk)*Nw + c0 + c;
        #pragma unroll
        for (int j=0;j<8;j++) f[j] = wp[j];
      }
      *(float4*)&Ws[kk][c]   = make_float4(f[0],f[1],f[2],f[3]);
      *(float4*)&Ws[kk][c+4] = make_float4(f[4],f[5],f[6],f[7]);
    }
    __syncthreads();
    #pragma unroll
    for (int k=0;k<32;k++){
      float a[4], b[4];
      #pragma unroll
      for (int i=0;i<4;i++) a[i] = As[k][ty*4 + i];
      #pragma unroll
      for (int j=0;j<4;j++) b[j] = Ws[k][tx*4 + j];
      #pragma unroll
      for (int i=0;i<4;i++)
        #pragma unroll
        for (int j=0;j<4;j++) acc[i][j] = fmaf(a[i], b[j], acc[i][j]);
    }
    __syncthreads();
  }
  #pragma unroll
  for (int i=0;i<4;i++)
    #pragma unroll
    for (int j=0;j<4;j++)
      atomicAdd(&out[(size_t)(ty*4 + i)*Nw + c0 + tx*4 + j], acc[i][j]);
}

// fused single-slice head layer: out(64,512) = relu(A(64,512)@W(512,512) + bias)
__global__ __launch_bounds__(256) void head_fused512(const float* __restrict__ A,
    const float* __restrict__ W, const float* __restrict__ bias, float* __restrict__ out){
  __shared__ float As[32][68];
  __shared__ float Ws[32][68];
  const int tid = threadIdx.x;
  const int c0 = blockIdx.x*64;
  const int tx = tid & 15, ty = tid >> 4;
  float acc[4][4];
  #pragma unroll
  for (int i=0;i<4;i++)
    #pragma unroll
    for (int j=0;j<4;j++) acc[i][j]=0.f;
  for (int kt=0; kt<512; kt+=32){
    {
      int m = tid & 63, kk = (tid >> 6)*8;
      #pragma unroll
      for (int j=0;j<8;j++) As[kk+j][m] = A[(size_t)m*512 + kt + kk + j];
    }
    {
      int kk = tid >> 3, c = (tid & 7)*8;
      const float* wp = W + (size_t)(kt + kk)*512 + c0 + c;
      #pragma unroll
      for (int j=0;j<8;j++) Ws[kk][c+j] = wp[j];
    }
    __syncthreads();
    #pragma unroll
    for (int k=0;k<32;k++){
      float a[4], b[4];
      #pragma unroll
      for (int i=0;i<4;i++) a[i] = As[k][ty*4 + i];
      #pragma unroll
      for (int j=0;j<4;j++) b[j] = Ws[k][tx*4 + j];
      #pragma unroll
      for (int i=0;i<4;i++)
        #pragma unroll
        for (int j=0;j<4;j++) acc[i][j] = fmaf(a[i], b[j], acc[i][j]);
    }
    __syncthreads();
  }
  #pragma unroll
  for (int i=0;i<4;i++)
    #pragma unroll
    for (int j=0;j<4;j++){
      int ccol = c0 + tx*4 + j;
      out[(size_t)(ty*4 + i)*512 + ccol] = fmaxf(acc[i][j] + bias[ccol], 0.f);
    }
}

__global__ void k_bias_relu(float* __restrict__ buf, const float* __restrict__ bias, int Nw, int do_relu){
  int g = blockIdx.x*256 + threadIdx.x;
  if (g >= NBATCH*Nw) return;
  int c = g % Nw;
  float v = buf[g] + bias[c];
  buf[g] = do_relu ? fmaxf(v, 0.f) : v;
}

__global__ void k_tiny(const float* __restrict__ A, int K, const float* __restrict__ W, int Nw,
                       const float* __restrict__ bias, float* __restrict__ out){
  int g = threadIdx.x;
  if (g >= NBATCH*Nw) return;
  int b = g / Nw, c = g - b*Nw;
  float acc = bias[c];
  const float* a = A + (size_t)b*K;
  for (int k=0;k<K;k++) acc = fmaf(a[k], W[(size_t)k*Nw + c], acc);
  out[g] = acc;
}

__global__ void k_final(const float* __restrict__ pos, const float* __restrict__ sc,
                        const float* __restrict__ rot, const float* __restrict__ vec,
                        float* __restrict__ out){
  int g = blockIdx.x*256 + threadIdx.x;
  if (g >= NBATCH*8) return;
  int b = g >> 3, j = g & 7;
  float v;
  if (j < 2) v = pos[b*2 + j];
  else if (j == 2) v = sc[b];
  else if (j == 3) v = rot[b];
  else v = vec[b*4 + j - 4];
  out[g] = v;
}

// ---------------- host ----------------
static inline int cdiv(int a, int b){ return (a + b - 1)/b; }

extern "C" void kernel_launch(void* const* d_in, const int* in_sizes, int n_in,
                              void* d_out, int out_size, void* d_ws, size_t ws_size,
                              hipStream_t stream)
{
  (void)in_sizes; (void)n_in; (void)out_size;
  const float* x   = (const float*)d_in[0];
  const int* ei    = (const int*)d_in[1];
  const int* batch = (const int*)d_in[2];
  const float* tpos= (const float*)d_in[3];
  const float* W1 = (const float*)d_in[4];  const float* b1 = (const float*)d_in[5];
  const float* W2 = (const float*)d_in[6];  const float* b2 = (const float*)d_in[7];
  const float* W3 = (const float*)d_in[8];  const float* b3 = (const float*)d_in[9];
  const float* ph1w = (const float*)d_in[10]; const float* ph1b = (const float*)d_in[11];
  const float* ph2w = (const float*)d_in[12]; const float* ph2b = (const float*)d_in[13];
  const float* posw = (const float*)d_in[14]; const float* posb = (const float*)d_in[15];
  const float* vh1w = (const float*)d_in[16]; const float* vh1b = (const float*)d_in[17];
  const float* vh2w = (const float*)d_in[18]; const float* vh2b = (const float*)d_in[19];
  const float* vecw = (const float*)d_in[20]; const float* vecb = (const float*)d_in[21];
  const float* sh1w = (const float*)d_in[22]; const float* sh1b = (const float*)d_in[23];
  const float* sh2w = (const float*)d_in[24]; const float* sh2b = (const float*)d_in[25];
  const float* scw  = (const float*)d_in[26]; const float* scb  = (const float*)d_in[27];
  const float* rh1w = (const float*)d_in[28]; const float* rh1b = (const float*)d_in[29];
  const float* rh2w = (const float*)d_in[30]; const float* rh2b = (const float*)d_in[31];
  const float* rotw = (const float*)d_in[32]; const float* rotb = (const float*)d_in[33];
  float* out = (float*)d_out;

  char* w = (char*)d_ws;
  size_t off = 0;
  auto alloc = [&](size_t bytes) -> void* {
    void* p = w + off;
    off = (off + bytes + 255) & ~(size_t)255;
    return p;
  };
  u16* h2b    = (u16*)alloc((size_t)NN*HC*2);
  u16* actb   = (u16*)alloc((size_t)NN*HC*2);
  u16* Wt2    = (u16*)alloc((size_t)HC*HC*2);
  u16* Wt3    = (u16*)alloc((size_t)HC*HC*2);
  float* dis  = (float*)alloc((size_t)NN*4);
  int* degc   = (int*)alloc((size_t)NN*4);
  int* rowp   = (int*)alloc((size_t)(NN+1)*4);
  int* cursor = (int*)alloc((size_t)NN*4);
  int* col    = (int*)alloc((size_t)NE*4);
  int* gcnt   = (int*)alloc((size_t)NBATCH*4);
  int* gstart = (int*)alloc((size_t)NBATCH*4);
  u64* key1   = (u64*)alloc((size_t)NBATCH*8);
  u64* key2   = (u64*)alloc((size_t)NBATCH*8);
  float* gsum = (float*)alloc((size_t)NBATCH*HC*4);
  float* comb = (float*)alloc((size_t)NBATCH*DC*4);
  float* in0  = (float*)alloc((size_t)NBATCH*3098*4);
  float* t1   = (float*)alloc((size_t)NBATCH*1536*4);
  float* t2   = (float*)alloc((size_t)NBATCH*1536*4);
  float* inv  = (float*)alloc((size_t)NBATCH*3098*4);
  float* u1   = (float*)alloc((size_t)NBATCH*512*4);
  float* u2   = (float*)alloc((size_t)NBATCH*512*4);
  float* pvc  = (float*)alloc((size_t)NBATCH*3102*4);
  float* sb1  = (float*)alloc((size_t)NBATCH*512*4);
  float* sb2  = (float*)alloc((size_t)NBATCH*512*4);
  float* rb1  = (float*)alloc((size_t)NBATCH*512*4);
  float* rb2  = (float*)alloc((size_t)NBATCH*512*4);
  float* poso = (float*)alloc((size_t)NBATCH*2*4);
  float* veco = (float*)alloc((size_t)NBATCH*4*4);
  float* sco  = (float*)alloc((size_t)NBATCH*4);
  float* roto = (float*)alloc((size_t)NBATCH*4);
  if (off > ws_size) return;

  // ---- graph prep ----
  hipMemsetAsync(degc, 0, (size_t)NN*4, stream);
  hipMemsetAsync(cursor, 0, (size_t)NN*4, stream);
  hipMemsetAsync(gcnt, 0, (size_t)NBATCH*4, stream);
  hipMemsetAsync(key1, 0xFF, (size_t)NBATCH*8, stream);
  hipMemsetAsync(key2, 0xFF, (size_t)NBATCH*8, stream);

  k_deg<<<cdiv(NE,256),256,0,stream>>>(ei, degc);
  k_gcnt<<<cdiv(NN,256),256,0,stream>>>(batch, gcnt);
  k_dis<<<cdiv(NN,256),256,0,stream>>>(degc, dis);
  k_scan<<<1,1024,0,stream>>>(degc, rowp);
  k_gstart<<<1,64,0,stream>>>(gcnt, gstart);
  k_fill<<<cdiv(NE,256),256,0,stream>>>(ei, rowp, cursor, col);
  k_face1<<<cdiv(NN,256),256,0,stream>>>(x, batch, key1);
  k_face2<<<cdiv(NN,256),256,0,stream>>>(x, batch, key1, key2);
  k_face3<<<1,64,0,stream>>>(x, key1, key2, comb);
  k_convWT<<<dim3(16,16),256,0,stream>>>(W2, Wt2);
  k_convWT<<<dim3(16,16),256,0,stream>>>(W3, Wt3);

  // ---- GCN layers ----
  k_gemm1<<<cdiv(NN*HC,256),256,0,stream>>>(x, W1, h2b);
  k_agg<<<cdiv(NN,4),256,0,stream>>>(h2b, dis, rowp, col, b1, actb);
  hipMemsetAsync(gsum, 0, (size_t)NBATCH*HC*4, stream);
  k_readout<<<NBATCH*4,256,0,stream>>>(actb, gstart, gcnt, gsum);
  k_readout_write<<<cdiv(NBATCH*HC,256),256,0,stream>>>(gsum, gcnt, comb, 0);

  gemm_mfma<<<cdiv(NN/16,4),256,0,stream>>>(actb, Wt2, h2b, NN);
  k_agg<<<cdiv(NN,4),256,0,stream>>>(h2b, dis, rowp, col, b2, actb);
  hipMemsetAsync(gsum, 0, (size_t)NBATCH*HC*4, stream);
  k_readout<<<NBATCH*4,256,0,stream>>>(actb, gstart, gcnt, gsum);
  k_readout_write<<<cdiv(NBATCH*HC,256),256,0,stream>>>(gsum, gcnt, comb, 1);

  gemm_mfma<<<cdiv(NN/16,4),256,0,stream>>>(actb, Wt3, h2b, NN);
  k_agg<<<cdiv(NN,4),256,0,stream>>>(h2b, dis, rowp, col, b3, actb);
  hipMemsetAsync(gsum, 0, (size_t)NBATCH*HC*4, stream);
  k_readout<<<NBATCH*4,256,0,stream>>>(actb, gstart, gcnt, gsum);
  k_readout_write<<<cdiv(NBATCH*HC,256),256,0,stream>>>(gsum, gcnt, comb, 2);

  // ---- pos head ----
  k_in0<<<cdiv(NBATCH*3098,256),256,0,stream>>>(tpos, comb, in0);
  hipMemsetAsync(t1, 0, (size_t)NBATCH*1536*4, stream);
  head_gemm<<<dim3(1536/64, cdiv(3098,800)),256,0,stream>>>(in0, 3098, ph1w, 1536, t1);
  k_bias_relu<<<cdiv(NBATCH*1536,256),256,0,stream>>>(t1, ph1b, 1536, 1);
  hipMemsetAsync(t2, 0, (size_t)NBATCH*1536*4, stream);
  head_gemm<<<dim3(1536/64, cdiv(1536,800)),256,0,stream>>>(t1, 1536, ph2w, 1536, t2);
  k_bias_relu<<<cdiv(NBATCH*1536,256),256,0,stream>>>(t2, ph2b, 1536, 1);
  k_tiny<<<1,256,0,stream>>>(t2, 1536, posw, 2, posb, poso);

  // ---- vec head ----
  k_inv<<<cdiv(NBATCH*3098,256),256,0,stream>>>(poso, comb, inv);
  hipMemsetAsync(u1, 0, (size_t)NBATCH*512*4, stream);
  head_gemm<<<dim3(512/64, cdiv(3098,800)),256,0,stream>>>(inv, 3098, vh1w, 512, u1);
  k_bias_relu<<<cdiv(NBATCH*512,256),256,0,stream>>>(u1, vh1b, 512, 1);
  head_fused512<<<8,256,0,stream>>>(u1, vh2w, vh2b, u2);
  k_tiny<<<1,256,0,stream>>>(u2, 512, vecw, 4, vecb, veco);

  // ---- pvc ----
  k_pvc<<<cdiv(NBATCH*3102,256),256,0,stream>>>(poso, veco, comb, pvc);

  // ---- scale head ----
  hipMemsetAsync(sb1, 0, (size_t)NBATCH*512*4, stream);
  head_gemm<<<dim3(512/64, cdiv(3102,800)),256,0,stream>>>(pvc, 3102, sh1w, 512, sb1);
  k_bias_relu<<<cdiv(NBATCH*512,256),256,0,stream>>>(sb1, sh1b, 512, 1);
  head_fused512<<<8,256,0,stream>>>(sb1, sh2w, sh2b, sb2);
  k_tiny<<<1,256,0,stream>>>(sb2, 512, scw, 1, scb, sco);

  // ---- rot head ----
  hipMemsetAsync(rb1, 0, (size_t)NBATCH*512*4, stream);
  head_gemm<<<dim3(512/64, cdiv(3102,800)),256,0,stream>>>(pvc, 3102, rh1w, 512, rb1);
  k_bias_relu<<<cdiv(NBATCH*512,256),256,0,stream>>>(rb1, rh1b, 512, 1);
  head_fused512<<<8,256,0,stream>>>(rb1, rh2w, rh2b, rb2);
  k_tiny<<<1,256,0,stream>>>(rb2, 512, rotw, 1, rotb, roto);

  // ---- final output ----
  k_final<<<cdiv(NBATCH*8,256),256,0,stream>>>(poso, sco, roto, veco, out);
}